// Round 1
// baseline (4177.092 us; speedup 1.0000x reference)
//
#include <hip/hip_runtime.h>
#include <math.h>

#define B_   16
#define S1_  61
#define S_   3721
#define D_   128
#define H_   8
#define DH_  16
#define NW_  61
#define WIN_ 61
#define PCH_ 49
#define FF_  512
#define BS_  (B_*S_)   // 59536

// ---------------- conv (7x7, same padding, relu) -> p [BS, 49] ----------------
__global__ __launch_bounds__(256) void conv_kernel(const float* __restrict__ x,
                                                   const float* __restrict__ cw,
                                                   const float* __restrict__ cb,
                                                   float* __restrict__ p) {
  int t = blockIdx.x * 256 + threadIdx.x;
  if (t >= B_ * S_ * PCH_) return;
  int c = t % PCH_;
  int s = (t / PCH_) % S_;
  int b = t / (PCH_ * S_);
  int i = s / S1_, j = s % S1_;
  float acc = cb[c];
  for (int di = 0; di < 7; di++) {
    int ii = i + di - 3;
    if (ii < 0 || ii >= S1_) continue;
    for (int dj = 0; dj < 7; dj++) {
      int jj = j + dj - 3;
      if (jj < 0 || jj >= S1_) continue;
      acc = fmaf(x[(b * S1_ + ii) * S1_ + jj], cw[c * 49 + di * 7 + dj], acc);
    }
  }
  p[t] = fmaxf(acc, 0.f);
}

// ---------------- generic tiled fp32 GEMM, 64x64 tile, 4x4/thread ----------------
enum { EPI_NONE = 0, EPI_BIAS_POS = 1, EPI_RES = 2, EPI_GELU = 3 };

template <int EPI>
__global__ __launch_bounds__(256) void gemm_k(
    const float* __restrict__ A, int lda,
    const float* __restrict__ Bm, int ldb,
    float* __restrict__ C, int ldc,
    int M, int N, int K,
    const float* __restrict__ bias,
    const float* __restrict__ pos) {
  __shared__ float As[16][64];
  __shared__ float Bs[16][64];
  int bm = blockIdx.y * 64;
  int bn = blockIdx.x * 64;
  int tid = threadIdx.x;
  int tn = tid & 15, tm = tid >> 4;
  float acc[4][4] = {};
  int arow = tid >> 2;          // 0..63
  int akq  = (tid & 3) << 2;    // 0,4,8,12
  int bn0  = tid & 63;
  int bk0  = tid >> 6;          // 0..3
  for (int k0 = 0; k0 < K; k0 += 16) {
    #pragma unroll
    for (int u = 0; u < 4; u++) {
      int kk = akq + u;
      int gm = bm + arow, gk = k0 + kk;
      As[kk][arow] = (gm < M && gk < K) ? A[(size_t)gm * lda + gk] : 0.f;
    }
    #pragma unroll
    for (int u = 0; u < 4; u++) {
      int kk = bk0 + u * 4;
      int gk = k0 + kk, gn = bn + bn0;
      Bs[kk][bn0] = (gk < K && gn < N) ? Bm[(size_t)gk * ldb + gn] : 0.f;
    }
    __syncthreads();
    #pragma unroll
    for (int kk = 0; kk < 16; kk++) {
      float a[4], b[4];
      #pragma unroll
      for (int i = 0; i < 4; i++) a[i] = As[kk][tm * 4 + i];
      #pragma unroll
      for (int j = 0; j < 4; j++) b[j] = Bs[kk][tn * 4 + j];
      #pragma unroll
      for (int i = 0; i < 4; i++)
        #pragma unroll
        for (int j = 0; j < 4; j++)
          acc[i][j] = fmaf(a[i], b[j], acc[i][j]);
    }
    __syncthreads();
  }
  #pragma unroll
  for (int i = 0; i < 4; i++) {
    int m = bm + tm * 4 + i;
    if (m >= M) continue;
    #pragma unroll
    for (int j = 0; j < 4; j++) {
      int n = bn + tn * 4 + j;
      if (n >= N) continue;
      float v = acc[i][j];
      if (EPI == EPI_BIAS_POS) {
        v += bias[n] + pos[(size_t)(m % S_) * D_ + n];
      } else if (EPI == EPI_RES) {
        v += C[(size_t)m * ldc + n];
        if (bias) v += bias[n];
      } else if (EPI == EPI_GELU) {
        v += bias[n];
        v = 0.5f * v * (1.f + erff(v * 0.70710678118654752f));
      }
      C[(size_t)m * ldc + n] = v;
    }
  }
}

// ---------------- LayerNorm: one wave (64 lanes) per row of 128 ----------------
__global__ __launch_bounds__(256) void ln_kernel(const float* __restrict__ x,
                                                 float* __restrict__ y,
                                                 const float* __restrict__ g,
                                                 const float* __restrict__ bta,
                                                 int rows) {
  int wave = (blockIdx.x * 256 + threadIdx.x) >> 6;
  int lane = threadIdx.x & 63;
  if (wave >= rows) return;
  const float* xr = x + (size_t)wave * D_;
  float x0 = xr[lane], x1 = xr[lane + 64];
  float sum = x0 + x1;
  #pragma unroll
  for (int off = 32; off; off >>= 1) sum += __shfl_xor(sum, off);
  float mean = sum * (1.f / 128.f);
  float d0 = x0 - mean, d1 = x1 - mean;
  float vs = d0 * d0 + d1 * d1;
  #pragma unroll
  for (int off = 32; off; off >>= 1) vs += __shfl_xor(vs, off);
  float inv = rsqrtf(vs * (1.f / 128.f) + 1e-5f);
  float* yr = y + (size_t)wave * D_;
  yr[lane]      = d0 * inv * g[lane]      + bta[lane];
  yr[lane + 64] = d1 * inv * g[lane + 64] + bta[lane + 64];
}

// ---------------- windowed local attention, one block per (b, head, window) ----------------
__global__ __launch_bounds__(64) void attn_kernel(const float* __restrict__ Q,
                                                  const float* __restrict__ Kb,
                                                  const float* __restrict__ Vb,
                                                  float* __restrict__ O) {
  int bid = blockIdx.x;
  int w  = bid % NW_;
  int hh = (bid / NW_) % H_;
  int b  = bid / (NW_ * H_);
  __shared__ float ks[3 * WIN_][DH_];
  __shared__ float vs[3 * WIN_][DH_];
  int tid = threadIdx.x;
  for (int idx = tid; idx < 3 * WIN_ * DH_; idx += 64) {
    int j = idx >> 4, d = idx & 15;
    int jb = j / WIN_, jj = j % WIN_;
    int wk = w - 1 + jb;
    float kv = 0.f, vv = 0.f;
    if (wk >= 0 && wk < NW_) {
      size_t row = (size_t)(b * S_ + wk * WIN_ + jj);
      kv = Kb[row * D_ + hh * DH_ + d];
      vv = Vb[row * D_ + hh * DH_ + d];
    }
    ks[j][d] = kv;
    vs[j][d] = vv;
  }
  __syncthreads();
  int r = tid;
  if (r >= WIN_) return;
  size_t qrow = (size_t)(b * S_ + w * WIN_ + r);
  float qreg[DH_];
  #pragma unroll
  for (int d = 0; d < DH_; d++) qreg[d] = Q[qrow * D_ + hh * DH_ + d] * 0.25f;  // DH^-0.5
  int j0 = (w == 0) ? WIN_ : 0;
  int j1 = (w == NW_ - 1) ? 2 * WIN_ : 3 * WIN_;
  float mx = -1e30f, l = 0.f;
  float out[DH_];
  #pragma unroll
  for (int d = 0; d < DH_; d++) out[d] = 0.f;
  for (int j = j0; j < j1; j++) {
    float s = 0.f;
    #pragma unroll
    for (int d = 0; d < DH_; d++) s = fmaf(qreg[d], ks[j][d], s);
    if (s > mx) {
      float sc = expf(mx - s);
      l *= sc;
      #pragma unroll
      for (int d = 0; d < DH_; d++) out[d] *= sc;
      mx = s;
    }
    float e = expf(s - mx);
    l += e;
    #pragma unroll
    for (int d = 0; d < DH_; d++) out[d] = fmaf(e, vs[j][d], out[d]);
  }
  float invl = 1.f / l;
  #pragma unroll
  for (int d = 0; d < DH_; d++) O[qrow * D_ + hh * DH_ + d] = out[d] * invl;
}

// ---------------- fused head: relu(h@W1+b1)@W2 + b2, one block (128 thr) per row ----------------
__global__ __launch_bounds__(128) void head_kernel(const float* __restrict__ h,
                                                   const float* __restrict__ w1,
                                                   const float* __restrict__ b1,
                                                   const float* __restrict__ w2,
                                                   const float* __restrict__ b2,
                                                   float* __restrict__ out) {
  int row = blockIdx.x;
  int n = threadIdx.x;
  __shared__ float xr[D_];
  xr[n] = h[(size_t)row * D_ + n];
  __syncthreads();
  float acc = b1[n];
  #pragma unroll 8
  for (int k = 0; k < D_; k++) acc = fmaf(xr[k], w1[k * D_ + n], acc);
  acc = fmaxf(acc, 0.f) * w2[n];
  #pragma unroll
  for (int off = 32; off; off >>= 1) acc += __shfl_xor(acc, off);
  __shared__ float partial[2];
  if ((n & 63) == 0) partial[n >> 6] = acc;
  __syncthreads();
  if (n == 0) out[row] = partial[0] + partial[1] + b2[0];
}

extern "C" void kernel_launch(void* const* d_in, const int* in_sizes, int n_in,
                              void* d_out, int out_size, void* d_ws, size_t ws_size,
                              hipStream_t stream) {
  const float* x      = (const float*)d_in[0];
  const float* conv_w = (const float*)d_in[1];
  const float* conv_b = (const float*)d_in[2];
  const float* lt_w   = (const float*)d_in[3];
  const float* lt_b   = (const float*)d_in[4];
  const float* pos    = (const float*)d_in[5];
  const float* ln1_s  = (const float*)d_in[6];
  const float* ln1_b  = (const float*)d_in[7];
  const float* wq     = (const float*)d_in[8];
  const float* wk     = (const float*)d_in[9];
  const float* wv     = (const float*)d_in[10];
  const float* wo     = (const float*)d_in[11];
  const float* wo_b   = (const float*)d_in[12];
  const float* ln2_s  = (const float*)d_in[13];
  const float* ln2_b  = (const float*)d_in[14];
  const float* ff_w1  = (const float*)d_in[15];
  const float* ff_b1  = (const float*)d_in[16];
  const float* ff_w2  = (const float*)d_in[17];
  const float* ff_b2  = (const float*)d_in[18];
  const float* pre_w1 = (const float*)d_in[19];
  const float* pre_b1 = (const float*)d_in[20];
  const float* pre_w2 = (const float*)d_in[21];
  const float* pre_b2 = (const float*)d_in[22];

  char* ws = (char*)d_ws;
  const size_t BUF = (size_t)BS_ * D_ * sizeof(float);  // ~29.1 MiB
  float* h  = (float*)(ws);
  float* hn = (float*)(ws + BUF);
  float* q  = (float*)(ws + 2 * BUF);
  float* k  = (float*)(ws + 3 * BUF);
  float* v  = (float*)(ws + 4 * BUF);
  float* o  = (float*)(ws + 5 * BUF);
  float* p  = q;  // conv patches [BS,49] — reuse q region (dead at that point)
  float* t  = q;  // FF intermediate [BS,512] — spans q..o (dead during FF)

  // conv -> p
  int nconv = B_ * S_ * PCH_;
  conv_kernel<<<dim3((nconv + 255) / 256), 256, 0, stream>>>(x, conv_w, conv_b, p);

  // h = p @ lt_w + lt_b + pos[:S]
  dim3 gH((D_ + 63) / 64, (BS_ + 63) / 64);
  gemm_k<EPI_BIAS_POS><<<gH, 256, 0, stream>>>(p, PCH_, lt_w, D_, h, D_, BS_, D_, PCH_, lt_b, pos);

  dim3 gF1((FF_ + 63) / 64, (BS_ + 63) / 64);
  int lnBlocks = (BS_ + 3) / 4;

  for (int l = 0; l < 4; l++) {
    // hn = LN1(h)
    ln_kernel<<<dim3(lnBlocks), 256, 0, stream>>>(h, hn, ln1_s + l * D_, ln1_b + l * D_, BS_);
    // q,k,v
    gemm_k<EPI_NONE><<<gH, 256, 0, stream>>>(hn, D_, wq + (size_t)l * D_ * D_, D_, q, D_, BS_, D_, D_, nullptr, nullptr);
    gemm_k<EPI_NONE><<<gH, 256, 0, stream>>>(hn, D_, wk + (size_t)l * D_ * D_, D_, k, D_, BS_, D_, D_, nullptr, nullptr);
    gemm_k<EPI_NONE><<<gH, 256, 0, stream>>>(hn, D_, wv + (size_t)l * D_ * D_, D_, v, D_, BS_, D_, D_, nullptr, nullptr);
    // windowed attention -> o
    attn_kernel<<<dim3(B_ * H_ * NW_), 64, 0, stream>>>(q, k, v, o);
    // h += o @ wo + wo_b
    gemm_k<EPI_RES><<<gH, 256, 0, stream>>>(o, D_, wo + (size_t)l * D_ * D_, D_, h, D_, BS_, D_, D_, wo_b + l * D_, nullptr);
    // hn = LN2(h)
    ln_kernel<<<dim3(lnBlocks), 256, 0, stream>>>(h, hn, ln2_s + l * D_, ln2_b + l * D_, BS_);
    // t = gelu(hn @ ff_w1 + ff_b1)
    gemm_k<EPI_GELU><<<gF1, 256, 0, stream>>>(hn, D_, ff_w1 + (size_t)l * D_ * FF_, FF_, t, FF_, BS_, FF_, D_, ff_b1 + l * FF_, nullptr);
    // h += t @ ff_w2 + ff_b2
    gemm_k<EPI_RES><<<gH, 256, 0, stream>>>(t, FF_, ff_w2 + (size_t)l * FF_ * D_, D_, h, D_, BS_, D_, FF_, ff_b2 + l * D_, nullptr);
  }

  // out = relu(h @ pre_w1 + pre_b1) @ pre_w2 + pre_b2
  head_kernel<<<dim3(BS_), 128, 0, stream>>>(h, pre_w1, pre_b1, pre_w2, pre_b2, (float*)d_out);
}

// Round 2
// 1548.026 us; speedup vs baseline: 2.6983x; 2.6983x over previous
//
#include <hip/hip_runtime.h>
#include <math.h>

#define B_   16
#define S1_  61
#define S_   3721
#define D_   128
#define H_   8
#define NW_  61
#define FF_  512
#define BS_  (B_*S_)   // 59536

typedef unsigned int   uint32;
typedef unsigned short ushort16;
typedef __attribute__((ext_vector_type(8))) short  short8;
typedef __attribute__((ext_vector_type(4))) float  floatx4;

__device__ __forceinline__ ushort16 f2bf(float f) {
  uint32 u = __float_as_uint(f);
  uint32 r = u + 0x7fffu + ((u >> 16) & 1u);   // RNE
  return (ushort16)(r >> 16);
}

// ---------------- weight prep: fp32 -> bf16, transposed to [N][K] ----------------
// regions: qkv_t 4*384*128 | wo_t 4*128*128 | w1_t 4*512*128 | w2_t 4*128*512 | lt_t 128*64 | pw1_t 128*128
__global__ __launch_bounds__(256) void prep_w(
    const float* __restrict__ wq, const float* __restrict__ wk, const float* __restrict__ wv,
    const float* __restrict__ wo, const float* __restrict__ w1, const float* __restrict__ w2,
    const float* __restrict__ lt, const float* __restrict__ pw1,
    ushort16* __restrict__ qkv_t, ushort16* __restrict__ wo_t, ushort16* __restrict__ w1_t,
    ushort16* __restrict__ w2_t, ushort16* __restrict__ lt_t, ushort16* __restrict__ pw1_t) {
  int i = blockIdx.x * 256 + threadIdx.x;
  if (i < 196608) {                       // qkv: [l][n(384)][k(128)]
    int l = i / 49152, r = i % 49152;
    int n = r / 128, k = r % 128;
    const float* src = (n < 128) ? wq : (n < 256) ? wk : wv;
    qkv_t[i] = f2bf(src[(l * 128 + k) * 128 + (n & 127)]);
  } else if (i < 262144) {                // wo: [l][n][k]
    int j = i - 196608;
    int l = j / 16384, r = j % 16384;
    int n = r / 128, k = r % 128;
    wo_t[j] = f2bf(wo[(l * 128 + k) * 128 + n]);
  } else if (i < 524288) {                // w1: [l][n(512)][k(128)]
    int j = i - 262144;
    int l = j / 65536, r = j % 65536;
    int n = r / 128, k = r % 128;
    w1_t[j] = f2bf(w1[(size_t)l * 65536 + k * 512 + n]);
  } else if (i < 786432) {                // w2: [l][n(128)][k(512)]
    int j = i - 524288;
    int l = j / 65536, r = j % 65536;
    int n = r / 512, k = r % 512;
    w2_t[j] = f2bf(w2[(size_t)l * 65536 + k * 128 + n]);
  } else if (i < 794624) {                // lt: [n(128)][k(64 padded from 49)]
    int j = i - 786432;
    int n = j / 64, k = j % 64;
    lt_t[j] = f2bf(k < 49 ? lt[k * 128 + n] : 0.f);
  } else if (i < 811008) {                // pre_w1: [n][k]
    int j = i - 794624;
    int n = j / 128, k = j % 128;
    pw1_t[j] = f2bf(pw1[k * 128 + n]);
  }
}

// ---------------- conv (7x7 same, relu) -> bf16 patches [BS][64], cols 49..63 = 0 ----
__global__ __launch_bounds__(256) void conv_bf16(const float* __restrict__ x,
                                                 const float* __restrict__ cw,
                                                 const float* __restrict__ cb,
                                                 ushort16* __restrict__ p) {
  int t = blockIdx.x * 256 + threadIdx.x;
  if (t >= BS_ * 64) return;
  int c = t & 63;
  if (c >= 49) { p[t] = 0; return; }
  int row = t >> 6;
  int b = row / S_, s = row % S_;
  int i = s / S1_, j = s % S1_;
  float acc = cb[c];
  for (int di = 0; di < 7; di++) {
    int ii = i + di - 3;
    if (ii < 0 || ii >= S1_) continue;
    for (int dj = 0; dj < 7; dj++) {
      int jj = j + dj - 3;
      if (jj < 0 || jj >= S1_) continue;
      acc = fmaf(x[(b * S1_ + ii) * S1_ + jj], cw[c * 49 + di * 7 + dj], acc);
    }
  }
  p[t] = f2bf(fmaxf(acc, 0.f));
}

// ---------------- bf16 MFMA GEMM: C[M x N] = A[M x K] * Bt[N x K]^T ----------------
// 128x128 tile, BK=64, 256 threads = 4 waves each computing a 64x64 quadrant.
enum { E_BF16 = 0, E_H0 = 1, E_RES = 2, E_GELU = 3, E_RELU = 4, E_RESBF = 5 };

template <int EPI>
__global__ __launch_bounds__(256) void gemm_bf16(
    const ushort16* __restrict__ A, int lda,
    const ushort16* __restrict__ Bt, int ldbt,
    float* __restrict__ H,                 // fp32 output (H0/RES/RESBF), ld 128
    ushort16* __restrict__ Cb, int ldc,    // bf16 output
    const float* __restrict__ bias,
    const float* __restrict__ pos,
    int M, int K) {
  __shared__ ushort16 As[128][72];   // +8 pad: 144 B rows -> <=2-way banks
  __shared__ ushort16 Bs[128][72];
  int bm = blockIdx.y * 128, bn = blockIdx.x * 128;
  int tid = threadIdx.x;
  int lane = tid & 63, wave = tid >> 6;
  int wm = (wave >> 1) * 64, wn = (wave & 1) * 64;
  int ln = lane & 15, qd = lane >> 4;
  floatx4 acc[4][4] = {};
  for (int kc = 0; kc < K; kc += 64) {
    #pragma unroll
    for (int u = 0; u < 4; u++) {
      int id = tid + u * 256;
      int row = id >> 3, c = (id & 7) * 8;
      int gm = bm + row; if (gm > M - 1) gm = M - 1;
      *(uint4*)&As[row][c] = *(const uint4*)(A + (size_t)gm * lda + kc + c);
      *(uint4*)&Bs[row][c] = *(const uint4*)(Bt + (size_t)(bn + row) * ldbt + kc + c);
    }
    __syncthreads();
    #pragma unroll
    for (int ks = 0; ks < 64; ks += 32) {
      short8 af[4], bf[4];
      #pragma unroll
      for (int i = 0; i < 4; i++) af[i] = *(const short8*)&As[wm + i * 16 + ln][ks + qd * 8];
      #pragma unroll
      for (int j = 0; j < 4; j++) bf[j] = *(const short8*)&Bs[wn + j * 16 + ln][ks + qd * 8];
      #pragma unroll
      for (int i = 0; i < 4; i++)
        #pragma unroll
        for (int j = 0; j < 4; j++)
          acc[i][j] = __builtin_amdgcn_mfma_f32_16x16x32_bf16(af[i], bf[j], acc[i][j], 0, 0, 0);
    }
    __syncthreads();
  }
  // epilogue: D row = qd*4 + r, col = ln  (verified C/D layout)
  #pragma unroll
  for (int i = 0; i < 4; i++) {
    #pragma unroll
    for (int r = 0; r < 4; r++) {
      int gm = bm + wm + i * 16 + qd * 4 + r;
      if (gm >= M) continue;
      #pragma unroll
      for (int j = 0; j < 4; j++) {
        int gn = bn + wn + j * 16 + ln;
        float v = acc[i][j][r];
        if (EPI == E_BF16) {
          Cb[(size_t)gm * ldc + gn] = f2bf(v);
        } else if (EPI == E_H0) {
          H[(size_t)gm * 128 + gn] = v + bias[gn] + pos[(size_t)(gm % S_) * 128 + gn];
        } else if (EPI == E_RES) {
          size_t o = (size_t)gm * 128 + gn;
          H[o] += v + bias[gn];
        } else if (EPI == E_GELU) {
          float g = v + bias[gn];
          g = 0.5f * g * (1.f + erff(g * 0.70710678118654752f));
          Cb[(size_t)gm * ldc + gn] = f2bf(g);
        } else if (EPI == E_RELU) {
          float g = fmaxf(v + bias[gn], 0.f);
          Cb[(size_t)gm * ldc + gn] = f2bf(g);
        } else if (EPI == E_RESBF) {
          size_t o = (size_t)gm * 128 + gn;
          float g = H[o] + v + bias[gn];
          H[o] = g;
          Cb[(size_t)gm * ldc + gn] = f2bf(g);
        }
      }
    }
  }
}

// ---------------- LayerNorm: fp32 in, bf16 out, one wave per row ----------------
__global__ __launch_bounds__(256) void ln_bf16(const float* __restrict__ x,
                                               ushort16* __restrict__ y,
                                               const float* __restrict__ g,
                                               const float* __restrict__ bta,
                                               int rows) {
  int wv = (blockIdx.x * 256 + threadIdx.x) >> 6;
  int lane = threadIdx.x & 63;
  if (wv >= rows) return;
  const float* xr = x + (size_t)wv * D_;
  float x0 = xr[lane], x1 = xr[lane + 64];
  float sum = x0 + x1;
  #pragma unroll
  for (int off = 32; off; off >>= 1) sum += __shfl_xor(sum, off);
  float mean = sum * (1.f / 128.f);
  float d0 = x0 - mean, d1 = x1 - mean;
  float vs = d0 * d0 + d1 * d1;
  #pragma unroll
  for (int off = 32; off; off >>= 1) vs += __shfl_xor(vs, off);
  float inv = rsqrtf(vs * (1.f / 128.f) + 1e-5f);
  ushort16* yr = y + (size_t)wv * D_;
  yr[lane]      = f2bf(d0 * inv * g[lane]      + bta[lane]);
  yr[lane + 64] = f2bf(d1 * inv * g[lane + 64] + bta[lane + 64]);
}

// ---------------- windowed attention v2: bf16 K/V in LDS, single-pass softmax ----
// qkv bf16 [row][384] = q|k|v; one 64-thread block per (b,h,w); o bf16 [row][128]
__global__ __launch_bounds__(64) void attn2(const ushort16* __restrict__ qkv,
                                            ushort16* __restrict__ o) {
  int bid = blockIdx.x;
  int w  = bid % NW_;
  int hh = (bid / NW_) % H_;
  int b  = bid / (NW_ * H_);
  __shared__ ushort16 ks[192][16];
  __shared__ ushort16 vs[192][16];
  int tid = threadIdx.x;
  for (int idx = tid; idx < 366; idx += 64) {
    int j = idx >> 1, half = (idx & 1) * 8;
    int jb = j / 61, jj = j - jb * 61;
    int wk = w - 1 + jb;
    if (wk >= 0 && wk < NW_) {
      size_t base = (size_t)(b * S_ + wk * 61 + jj) * 384 + hh * 16 + half;
      *(uint4*)&ks[j][half] = *(const uint4*)(qkv + base + 128);
      *(uint4*)&vs[j][half] = *(const uint4*)(qkv + base + 256);
    }
  }
  int r = tid;
  size_t qrow = (size_t)b * S_ + w * 61 + r;
  if (qrow > (size_t)(BS_ - 1)) qrow = BS_ - 1;   // lanes 61..63 clamp
  float q[16];
  {
    const uint32* qp = (const uint32*)(qkv + qrow * 384 + hh * 16);
    #pragma unroll
    for (int i = 0; i < 8; i++) {
      uint32 u = qp[i];
      q[2 * i]     = __uint_as_float(u << 16) * 0.25f;           // DH^-0.5
      q[2 * i + 1] = __uint_as_float(u & 0xffff0000u) * 0.25f;
    }
  }
  __syncthreads();
  int j0 = (w == 0) ? 61 : 0;
  int j1 = (w == NW_ - 1) ? 122 : 183;
  float l = 0.f, out[16];
  #pragma unroll
  for (int d = 0; d < 16; d++) out[d] = 0.f;
  // scores bounded (|s| << 88): no max-subtraction needed, no overflow possible
  for (int j = j0; j < j1; ++j) {
    const uint32* kp = (const uint32*)&ks[j][0];
    float sp0 = 0.f, sp1 = 0.f, sp2 = 0.f, sp3 = 0.f;
    #pragma unroll
    for (int i = 0; i < 8; i += 4) {
      uint32 u0 = kp[i], u1 = kp[i + 1], u2 = kp[i + 2], u3 = kp[i + 3];
      sp0 = fmaf(q[2*i],   __uint_as_float(u0 << 16), sp0);
      sp0 = fmaf(q[2*i+1], __uint_as_float(u0 & 0xffff0000u), sp0);
      sp1 = fmaf(q[2*i+2], __uint_as_float(u1 << 16), sp1);
      sp1 = fmaf(q[2*i+3], __uint_as_float(u1 & 0xffff0000u), sp1);
      sp2 = fmaf(q[2*i+4], __uint_as_float(u2 << 16), sp2);
      sp2 = fmaf(q[2*i+5], __uint_as_float(u2 & 0xffff0000u), sp2);
      sp3 = fmaf(q[2*i+6], __uint_as_float(u3 << 16), sp3);
      sp3 = fmaf(q[2*i+7], __uint_as_float(u3 & 0xffff0000u), sp3);
    }
    float s = (sp0 + sp1) + (sp2 + sp3);
    float e = __expf(s);
    l += e;
    const uint32* vp = (const uint32*)&vs[j][0];
    #pragma unroll
    for (int i = 0; i < 8; i++) {
      uint32 u = vp[i];
      out[2*i]   = fmaf(e, __uint_as_float(u << 16), out[2*i]);
      out[2*i+1] = fmaf(e, __uint_as_float(u & 0xffff0000u), out[2*i+1]);
    }
  }
  if (r < 61) {
    float invl = 1.f / l;
    uint32 pk[8];
    #pragma unroll
    for (int i = 0; i < 8; i++) {
      uint32 lo = (uint32)f2bf(out[2*i] * invl);
      uint32 hi = (uint32)f2bf(out[2*i+1] * invl);
      pk[i] = lo | (hi << 16);
    }
    uint4* op = (uint4*)(o + qrow * 128 + hh * 16);
    op[0] = *(uint4*)&pk[0];
    op[1] = *(uint4*)&pk[4];
  }
}

// ---------------- head finish: out[row] = dot(t2[row], w2) + b2 (relu already applied) ----
__global__ __launch_bounds__(256) void head2(const ushort16* __restrict__ t2,
                                             const float* __restrict__ w2,
                                             const float* __restrict__ b2,
                                             float* __restrict__ out, int rows) {
  int wv = (blockIdx.x * 256 + threadIdx.x) >> 6;
  int lane = threadIdx.x & 63;
  if (wv >= rows) return;
  uint32 u = *(const uint32*)(t2 + (size_t)wv * 128 + lane * 2);
  float a = __uint_as_float(u << 16) * w2[lane * 2]
          + __uint_as_float(u & 0xffff0000u) * w2[lane * 2 + 1];
  #pragma unroll
  for (int off = 32; off; off >>= 1) a += __shfl_xor(a, off);
  if (lane == 0) out[wv] = a + b2[0];
}

extern "C" void kernel_launch(void* const* d_in, const int* in_sizes, int n_in,
                              void* d_out, int out_size, void* d_ws, size_t ws_size,
                              hipStream_t stream) {
  const float* x      = (const float*)d_in[0];
  const float* conv_w = (const float*)d_in[1];
  const float* conv_b = (const float*)d_in[2];
  const float* lt_w   = (const float*)d_in[3];
  const float* lt_b   = (const float*)d_in[4];
  const float* pos    = (const float*)d_in[5];
  const float* ln1_s  = (const float*)d_in[6];
  const float* ln1_b  = (const float*)d_in[7];
  const float* wq     = (const float*)d_in[8];
  const float* wk     = (const float*)d_in[9];
  const float* wv     = (const float*)d_in[10];
  const float* wo     = (const float*)d_in[11];
  const float* wo_b   = (const float*)d_in[12];
  const float* ln2_s  = (const float*)d_in[13];
  const float* ln2_b  = (const float*)d_in[14];
  const float* ff_w1  = (const float*)d_in[15];
  const float* ff_b1  = (const float*)d_in[16];
  const float* ff_w2  = (const float*)d_in[17];
  const float* ff_b2  = (const float*)d_in[18];
  const float* pre_w1 = (const float*)d_in[19];
  const float* pre_b1 = (const float*)d_in[20];
  const float* pre_w2 = (const float*)d_in[21];
  const float* pre_b2 = (const float*)d_in[22];

  char* ws = (char*)d_ws;
  const size_t SZ_H   = (size_t)BS_ * 128 * 4;   // 30,482,432
  const size_t SZ_HN  = (size_t)BS_ * 128 * 2;   // 15,241,216
  const size_t SZ_QKV = (size_t)BS_ * 384 * 2;   // 45,723,648
  const size_t SZ_O   = (size_t)BS_ * 128 * 2;
  float*    h    = (float*)ws;
  ushort16* hn   = (ushort16*)(ws + SZ_H);                      // also aliases p, hb
  ushort16* qkvb = (ushort16*)(ws + SZ_H + SZ_HN);              // also t (spans qkv+o)
  ushort16* ob   = (ushort16*)(ws + SZ_H + SZ_HN + SZ_QKV);     // also t2
  char*     wsw  = ws + SZ_H + SZ_HN + SZ_QKV + SZ_O;
  ushort16* qkv_t = (ushort16*)(wsw);
  ushort16* wo_t  = qkv_t + 196608;
  ushort16* w1_t  = wo_t  + 65536;
  ushort16* w2_t  = w1_t  + 262144;
  ushort16* lt_t  = w2_t  + 262144;
  ushort16* pw1_t = lt_t  + 8192;
  ushort16* p  = hn;        // conv patches [BS][64] bf16
  ushort16* t  = qkvb;      // FF intermediate [BS][512] bf16 (spans qkv+o regions)
  ushort16* hb = hn;        // bf16 copy of final h
  ushort16* t2 = ob;        // head hidden [BS][128] bf16

  prep_w<<<dim3(3168), 256, 0, stream>>>(wq, wk, wv, wo, ff_w1, ff_w2, lt_w, pre_w1,
                                         qkv_t, wo_t, w1_t, w2_t, lt_t, pw1_t);
  conv_bf16<<<dim3((BS_ * 64 + 255) / 256), 256, 0, stream>>>(x, conv_w, conv_b, p);

  const int MB = (BS_ + 127) / 128;  // 466
  // h = p @ lt_w + lt_b + pos
  gemm_bf16<E_H0><<<dim3(1, MB), 256, 0, stream>>>(p, 64, lt_t, 64, h, nullptr, 128, lt_b, pos, BS_, 64);

  int lnBlocks = (BS_ + 3) / 4;
  for (int l = 0; l < 4; l++) {
    ln_bf16<<<dim3(lnBlocks), 256, 0, stream>>>(h, hn, ln1_s + l * 128, ln1_b + l * 128, BS_);
    gemm_bf16<E_BF16><<<dim3(3, MB), 256, 0, stream>>>(hn, 128, qkv_t + (size_t)l * 49152, 128,
                                                       nullptr, qkvb, 384, nullptr, nullptr, BS_, 128);
    attn2<<<dim3(B_ * H_ * NW_), 64, 0, stream>>>(qkvb, ob);
    gemm_bf16<E_RES><<<dim3(1, MB), 256, 0, stream>>>(ob, 128, wo_t + (size_t)l * 16384, 128,
                                                      h, nullptr, 128, wo_b + l * 128, nullptr, BS_, 128);
    ln_bf16<<<dim3(lnBlocks), 256, 0, stream>>>(h, hn, ln2_s + l * 128, ln2_b + l * 128, BS_);
    gemm_bf16<E_GELU><<<dim3(4, MB), 256, 0, stream>>>(hn, 128, w1_t + (size_t)l * 65536, 128,
                                                       nullptr, t, 512, ff_b1 + l * 512, nullptr, BS_, 128);
    if (l < 3) {
      gemm_bf16<E_RES><<<dim3(1, MB), 256, 0, stream>>>(t, 512, w2_t + (size_t)l * 65536, 512,
                                                        h, nullptr, 128, ff_b2 + l * 128, nullptr, BS_, 512);
    } else {  // also emit bf16 copy of final h for the head GEMM
      gemm_bf16<E_RESBF><<<dim3(1, MB), 256, 0, stream>>>(t, 512, w2_t + (size_t)l * 65536, 512,
                                                          h, hb, 128, ff_b2 + l * 128, nullptr, BS_, 512);
    }
  }
  // head: t2 = relu(hb @ pre_w1 + pre_b1); out = t2 @ pre_w2 + pre_b2
  gemm_bf16<E_RELU><<<dim3(1, MB), 256, 0, stream>>>(hb, 128, pw1_t, 128,
                                                     nullptr, t2, 128, pre_b1, nullptr, BS_, 128);
  head2<<<dim3(lnBlocks), 256, 0, stream>>>(t2, pre_w2, pre_b2, (float*)d_out, BS_);
}

// Round 6
// 1165.187 us; speedup vs baseline: 3.5849x; 1.3286x over previous
//
#include <hip/hip_runtime.h>
#include <math.h>

#define B_   16
#define S1_  61
#define S_   3721
#define D_   128
#define H_   8
#define NW_  61
#define FF_  512
#define BS_  (B_*S_)   // 59536

typedef unsigned int   uint32;
typedef unsigned short ushort16;
typedef __attribute__((ext_vector_type(8))) short  short8;
typedef __attribute__((ext_vector_type(4))) float  floatx4;

__device__ __forceinline__ ushort16 f2bf(float f) {
  uint32 u = __float_as_uint(f);
  uint32 r = u + 0x7fffu + ((u >> 16) & 1u);   // RNE
  return (ushort16)(r >> 16);
}
__device__ __forceinline__ short bfs(float f) {  // bf16 RNE as short
  uint32 u = __float_as_uint(f);
  return (short)((u + 0x7fffu + ((u >> 16) & 1u)) >> 16);
}
__device__ __forceinline__ float bf2f(short s) { // bf16 bits -> float
  return __uint_as_float(((uint32)(ushort16)s) << 16);
}

// ---------------- weight prep: fp32 -> bf16, transposed to [N][K] ----------------
__global__ __launch_bounds__(256) void prep_w(
    const float* __restrict__ wq, const float* __restrict__ wk, const float* __restrict__ wv,
    const float* __restrict__ wo, const float* __restrict__ w1, const float* __restrict__ w2,
    const float* __restrict__ lt, const float* __restrict__ pw1,
    ushort16* __restrict__ qkv_t, ushort16* __restrict__ wo_t, ushort16* __restrict__ w1_t,
    ushort16* __restrict__ w2_t, ushort16* __restrict__ lt_t, ushort16* __restrict__ pw1_t) {
  int i = blockIdx.x * 256 + threadIdx.x;
  if (i < 196608) {                       // qkv: [l][n(384)][k(128)]
    int l = i / 49152, r = i % 49152;
    int n = r / 128, k = r % 128;
    const float* src = (n < 128) ? wq : (n < 256) ? wk : wv;
    qkv_t[i] = f2bf(src[(l * 128 + k) * 128 + (n & 127)]);
  } else if (i < 262144) {                // wo: [l][n][k]
    int j = i - 196608;
    int l = j / 16384, r = j % 16384;
    int n = r / 128, k = r % 128;
    wo_t[j] = f2bf(wo[(l * 128 + k) * 128 + n]);
  } else if (i < 524288) {                // w1: [l][n(512)][k(128)]
    int j = i - 262144;
    int l = j / 65536, r = j % 65536;
    int n = r / 128, k = r % 128;
    w1_t[j] = f2bf(w1[(size_t)l * 65536 + k * 512 + n]);
  } else if (i < 786432) {                // w2: [l][n(128)][k(512)]
    int j = i - 524288;
    int l = j / 65536, r = j % 65536;
    int n = r / 512, k = r % 512;
    w2_t[j] = f2bf(w2[(size_t)l * 65536 + k * 128 + n]);
  } else if (i < 794624) {                // lt: [n(128)][k(64 padded from 49)]
    int j = i - 786432;
    int n = j / 64, k = j % 64;
    lt_t[j] = f2bf(k < 49 ? lt[k * 128 + n] : 0.f);
  } else if (i < 811008) {                // pre_w1: [n][k]
    int j = i - 794624;
    int n = j / 128, k = j % 128;
    pw1_t[j] = f2bf(pw1[k * 128 + n]);
  }
}

// ---------------- conv (7x7 same, relu) -> bf16 patches [BS][64], cols 49..63 = 0 ----
__global__ __launch_bounds__(256) void conv_bf16(const float* __restrict__ x,
                                                 const float* __restrict__ cw,
                                                 const float* __restrict__ cb,
                                                 ushort16* __restrict__ p) {
  int t = blockIdx.x * 256 + threadIdx.x;
  if (t >= BS_ * 64) return;
  int c = t & 63;
  if (c >= 49) { p[t] = 0; return; }
  int row = t >> 6;
  int b = row / S_, s = row % S_;
  int i = s / S1_, j = s % S1_;
  float acc = cb[c];
  for (int di = 0; di < 7; di++) {
    int ii = i + di - 3;
    if (ii < 0 || ii >= S1_) continue;
    for (int dj = 0; dj < 7; dj++) {
      int jj = j + dj - 3;
      if (jj < 0 || jj >= S1_) continue;
      acc = fmaf(x[(b * S1_ + ii) * S1_ + jj], cw[c * 49 + di * 7 + dj], acc);
    }
  }
  p[t] = f2bf(fmaxf(acc, 0.f));
}

// ---------------- bf16 MFMA GEMM: C[M x N] = A[M x K] * Bt[N x K]^T ----------------
enum { E_BF16 = 0, E_H0 = 1, E_RES = 2, E_GELU = 3, E_RELU = 4, E_RESBF = 5 };

template <int EPI>
__global__ __launch_bounds__(256) void gemm_bf16(
    const ushort16* __restrict__ A, int lda,
    const ushort16* __restrict__ Bt, int ldbt,
    float* __restrict__ H,
    ushort16* __restrict__ Cb, int ldc,
    const float* __restrict__ bias,
    const float* __restrict__ pos,
    int M, int K) {
  __shared__ ushort16 As[128][72];
  __shared__ ushort16 Bs[128][72];
  int bm = blockIdx.y * 128, bn = blockIdx.x * 128;
  int tid = threadIdx.x;
  int lane = tid & 63, wave = tid >> 6;
  int wm = (wave >> 1) * 64, wn = (wave & 1) * 64;
  int ln = lane & 15, qd = lane >> 4;
  floatx4 acc[4][4] = {};
  for (int kc = 0; kc < K; kc += 64) {
    #pragma unroll
    for (int u = 0; u < 4; u++) {
      int id = tid + u * 256;
      int row = id >> 3, c = (id & 7) * 8;
      int gm = bm + row; if (gm > M - 1) gm = M - 1;
      *(uint4*)&As[row][c] = *(const uint4*)(A + (size_t)gm * lda + kc + c);
      *(uint4*)&Bs[row][c] = *(const uint4*)(Bt + (size_t)(bn + row) * ldbt + kc + c);
    }
    __syncthreads();
    #pragma unroll
    for (int ks = 0; ks < 64; ks += 32) {
      short8 af[4], bf[4];
      #pragma unroll
      for (int i = 0; i < 4; i++) af[i] = *(const short8*)&As[wm + i * 16 + ln][ks + qd * 8];
      #pragma unroll
      for (int j = 0; j < 4; j++) bf[j] = *(const short8*)&Bs[wn + j * 16 + ln][ks + qd * 8];
      #pragma unroll
      for (int i = 0; i < 4; i++)
        #pragma unroll
        for (int j = 0; j < 4; j++)
          acc[i][j] = __builtin_amdgcn_mfma_f32_16x16x32_bf16(af[i], bf[j], acc[i][j], 0, 0, 0);
    }
    __syncthreads();
  }
  #pragma unroll
  for (int i = 0; i < 4; i++) {
    #pragma unroll
    for (int r = 0; r < 4; r++) {
      int gm = bm + wm + i * 16 + qd * 4 + r;
      if (gm >= M) continue;
      #pragma unroll
      for (int j = 0; j < 4; j++) {
        int gn = bn + wn + j * 16 + ln;
        float v = acc[i][j][r];
        if (EPI == E_BF16) {
          Cb[(size_t)gm * ldc + gn] = f2bf(v);
        } else if (EPI == E_H0) {
          H[(size_t)gm * 128 + gn] = v + bias[gn] + pos[(size_t)(gm % S_) * 128 + gn];
        } else if (EPI == E_RES) {
          size_t o = (size_t)gm * 128 + gn;
          H[o] += v + bias[gn];
        } else if (EPI == E_GELU) {
          float g = v + bias[gn];
          g = 0.5f * g * (1.f + erff(g * 0.70710678118654752f));
          Cb[(size_t)gm * ldc + gn] = f2bf(g);
        } else if (EPI == E_RELU) {
          float g = fmaxf(v + bias[gn], 0.f);
          Cb[(size_t)gm * ldc + gn] = f2bf(g);
        } else if (EPI == E_RESBF) {
          size_t o = (size_t)gm * 128 + gn;
          float g = H[o] + v + bias[gn];
          H[o] = g;
          Cb[(size_t)gm * ldc + gn] = f2bf(g);
        }
      }
    }
  }
}

// ---------------- LayerNorm: fp32 in, bf16 out, one wave per row ----------------
__global__ __launch_bounds__(256) void ln_bf16(const float* __restrict__ x,
                                               ushort16* __restrict__ y,
                                               const float* __restrict__ g,
                                               const float* __restrict__ bta,
                                               int rows) {
  int wv = (blockIdx.x * 256 + threadIdx.x) >> 6;
  int lane = threadIdx.x & 63;
  if (wv >= rows) return;
  const float* xr = x + (size_t)wv * D_;
  float x0 = xr[lane], x1 = xr[lane + 64];
  float sum = x0 + x1;
  #pragma unroll
  for (int off = 32; off; off >>= 1) sum += __shfl_xor(sum, off);
  float mean = sum * (1.f / 128.f);
  float d0 = x0 - mean, d1 = x1 - mean;
  float vs = d0 * d0 + d1 * d1;
  #pragma unroll
  for (int off = 32; off; off >>= 1) vs += __shfl_xor(vs, off);
  float inv = rsqrtf(vs * (1.f / 128.f) + 1e-5f);
  ushort16* yr = y + (size_t)wv * D_;
  yr[lane]      = f2bf(d0 * inv * g[lane]      + bta[lane]);
  yr[lane + 64] = f2bf(d1 * inv * g[lane + 64] + bta[lane + 64]);
}

// ---------------- MFMA windowed attention, two-part P split: one wave per (b,h,w) --
// S^T = K.Q^T (dh=16 padded into K=32, elements e<4 per quad). S^T C-layout equals
// P A-layout for O = P.V. P fed as p_hi + p_lo (bf16 Dekker split).
// kt ranges: w==0 valid keys [61,183) -> kt 3..12; w==60 valid [0,122) -> kt 0..8.
__global__ __launch_bounds__(64) void attn3(const ushort16* __restrict__ qkv,
                                            ushort16* __restrict__ o) {
  int bid = blockIdx.x;
  int w  = bid % NW_;
  int hh = (bid / NW_) % H_;
  int b  = bid / (NW_ * H_);
  __shared__ ushort16 Kl[192][16];
  __shared__ ushort16 Vl[192][16];
  int lane = threadIdx.x;
  int qcol = lane & 15, quad = lane >> 4;

  for (int i = lane; i < 768; i += 64) {
    int isV = (i >= 384) ? 1 : 0;
    int r2 = isV ? (i - 384) : i;
    int j = r2 >> 1, half = (r2 & 1) * 8;
    int krow = (w - 1) * 61 + j;
    uint4 val = make_uint4(0u, 0u, 0u, 0u);
    if (j < 183 && (unsigned)krow < (unsigned)S_) {
      val = *(const uint4*)(qkv + ((size_t)(b * S_ + krow) * 384 + (isV ? 256 : 128) + hh * 16 + half));
    }
    if (isV) *(uint4*)&Vl[j][half] = val;
    else     *(uint4*)&Kl[j][half] = val;
  }

  short8 qf[4];
  #pragma unroll
  for (int qt = 0; qt < 4; qt++) {
    int qloc = qt * 16 + qcol;
    if (qloc > 60) qloc = 60;
    const uint32* qp = (const uint32*)(qkv + ((size_t)(b * S_ + w * 61 + qloc) * 384 + hh * 16 + quad * 4));
    uint32 u0 = qp[0], u1 = qp[1];
    short8 f = (short8)0;
    f[0] = (short)(u0 & 0xffffu); f[1] = (short)(u0 >> 16);
    f[2] = (short)(u1 & 0xffffu); f[3] = (short)(u1 >> 16);
    qf[qt] = f;
  }
  __syncthreads();

  int j0 = (w == 0) ? 61 : 0;
  int j1 = (w == NW_ - 1) ? 122 : 183;
  int kt0 = (w == 0) ? 3 : 0;
  int kt1 = (w == NW_ - 1) ? 8 : 12;

  floatx4 oacc[4];
  #pragma unroll
  for (int qt = 0; qt < 4; qt++) { oacc[qt][0]=0.f; oacc[qt][1]=0.f; oacc[qt][2]=0.f; oacc[qt][3]=0.f; }
  float lsum[4] = {0.f, 0.f, 0.f, 0.f};
  const floatx4 zero4 = {0.f, 0.f, 0.f, 0.f};

  for (int kt = kt0; kt < kt1; kt++) {
    const uint32* kp = (const uint32*)&Kl[kt * 16 + qcol][quad * 4];
    uint32 k0 = kp[0], k1 = kp[1];
    short8 kf = (short8)0;
    kf[0] = (short)(k0 & 0xffffu); kf[1] = (short)(k0 >> 16);
    kf[2] = (short)(k1 & 0xffffu); kf[3] = (short)(k1 >> 16);

    int kb = kt * 16 + quad * 4;
    short8 vf = (short8)0;
    vf[0] = (short)Vl[kb + 0][qcol];
    vf[1] = (short)Vl[kb + 1][qcol];
    vf[2] = (short)Vl[kb + 2][qcol];
    vf[3] = (short)Vl[kb + 3][qcol];

    floatx4 sacc[4];
    #pragma unroll
    for (int qt = 0; qt < 4; qt++)
      sacc[qt] = __builtin_amdgcn_mfma_f32_16x16x32_bf16(kf, qf[qt], zero4, 0, 0, 0);

    bool v0 = (unsigned)(kb + 0 - j0) < (unsigned)(j1 - j0);
    bool v1 = (unsigned)(kb + 1 - j0) < (unsigned)(j1 - j0);
    bool v2 = (unsigned)(kb + 2 - j0) < (unsigned)(j1 - j0);
    bool v3 = (unsigned)(kb + 3 - j0) < (unsigned)(j1 - j0);
    #pragma unroll
    for (int qt = 0; qt < 4; qt++) {
      float e0 = v0 ? __expf(fminf(sacc[qt][0] * 0.25f, 60.f)) : 0.f;
      float e1 = v1 ? __expf(fminf(sacc[qt][1] * 0.25f, 60.f)) : 0.f;
      float e2 = v2 ? __expf(fminf(sacc[qt][2] * 0.25f, 60.f)) : 0.f;
      float e3 = v3 ? __expf(fminf(sacc[qt][3] * 0.25f, 60.f)) : 0.f;
      lsum[qt] += (e0 + e1) + (e2 + e3);
      short h0 = bfs(e0), h1 = bfs(e1), h2 = bfs(e2), h3 = bfs(e3);
      short8 ph = (short8)0, pl = (short8)0;
      ph[0] = h0; ph[1] = h1; ph[2] = h2; ph[3] = h3;
      pl[0] = bfs(e0 - bf2f(h0));
      pl[1] = bfs(e1 - bf2f(h1));
      pl[2] = bfs(e2 - bf2f(h2));
      pl[3] = bfs(e3 - bf2f(h3));
      oacc[qt] = __builtin_amdgcn_mfma_f32_16x16x32_bf16(ph, vf, oacc[qt], 0, 0, 0);
      oacc[qt] = __builtin_amdgcn_mfma_f32_16x16x32_bf16(pl, vf, oacc[qt], 0, 0, 0);
    }
  }

  #pragma unroll
  for (int qt = 0; qt < 4; qt++) {
    float l = lsum[qt];
    l += __shfl_xor(l, 16);
    l += __shfl_xor(l, 32);
    lsum[qt] = 1.0f / fmaxf(l, 1e-30f);
  }
  #pragma unroll
  for (int qt = 0; qt < 4; qt++) {
    #pragma unroll
    for (int r = 0; r < 4; r++) {
      int qloc = qt * 16 + quad * 4 + r;
      float invl = __shfl(lsum[qt], quad * 4 + r);
      if (qloc < 61) {
        size_t row = (size_t)b * S_ + w * 61 + qloc;
        o[row * 128 + hh * 16 + qcol] = f2bf(oacc[qt][r] * invl);
      }
    }
  }
}

// ---------------- head finish ----------------
__global__ __launch_bounds__(256) void head2(const ushort16* __restrict__ t2,
                                             const float* __restrict__ w2,
                                             const float* __restrict__ b2,
                                             float* __restrict__ out, int rows) {
  int wv = (blockIdx.x * 256 + threadIdx.x) >> 6;
  int lane = threadIdx.x & 63;
  if (wv >= rows) return;
  uint32 u = *(const uint32*)(t2 + (size_t)wv * 128 + lane * 2);
  float a = __uint_as_float(u << 16) * w2[lane * 2]
          + __uint_as_float(u & 0xffff0000u) * w2[lane * 2 + 1];
  #pragma unroll
  for (int off = 32; off; off >>= 1) a += __shfl_xor(a, off);
  if (lane == 0) out[wv] = a + b2[0];
}

extern "C" void kernel_launch(void* const* d_in, const int* in_sizes, int n_in,
                              void* d_out, int out_size, void* d_ws, size_t ws_size,
                              hipStream_t stream) {
  const float* x      = (const float*)d_in[0];
  const float* conv_w = (const float*)d_in[1];
  const float* conv_b = (const float*)d_in[2];
  const float* lt_w   = (const float*)d_in[3];
  const float* lt_b   = (const float*)d_in[4];
  const float* pos    = (const float*)d_in[5];
  const float* ln1_s  = (const float*)d_in[6];
  const float* ln1_b  = (const float*)d_in[7];
  const float* wq     = (const float*)d_in[8];
  const float* wk     = (const float*)d_in[9];
  const float* wv     = (const float*)d_in[10];
  const float* wo     = (const float*)d_in[11];
  const float* wo_b   = (const float*)d_in[12];
  const float* ln2_s  = (const float*)d_in[13];
  const float* ln2_b  = (const float*)d_in[14];
  const float* ff_w1  = (const float*)d_in[15];
  const float* ff_b1  = (const float*)d_in[16];
  const float* ff_w2  = (const float*)d_in[17];
  const float* ff_b2  = (const float*)d_in[18];
  const float* pre_w1 = (const float*)d_in[19];
  const float* pre_b1 = (const float*)d_in[20];
  const float* pre_w2 = (const float*)d_in[21];
  const float* pre_b2 = (const float*)d_in[22];

  char* ws = (char*)d_ws;
  const size_t SZ_H   = (size_t)BS_ * 128 * 4;
  const size_t SZ_HN  = (size_t)BS_ * 128 * 2;
  const size_t SZ_QKV = (size_t)BS_ * 384 * 2;
  const size_t SZ_O   = (size_t)BS_ * 128 * 2;
  float*    h    = (float*)ws;
  ushort16* hn   = (ushort16*)(ws + SZ_H);
  ushort16* qkvb = (ushort16*)(ws + SZ_H + SZ_HN);
  ushort16* ob   = (ushort16*)(ws + SZ_H + SZ_HN + SZ_QKV);
  char*     wsw  = ws + SZ_H + SZ_HN + SZ_QKV + SZ_O;
  ushort16* qkv_t = (ushort16*)(wsw);
  ushort16* wo_t  = qkv_t + 196608;
  ushort16* w1_t  = wo_t  + 65536;
  ushort16* w2_t  = w1_t  + 262144;
  ushort16* lt_t  = w2_t  + 262144;
  ushort16* pw1_t = lt_t  + 8192;
  ushort16* p  = hn;
  ushort16* t  = qkvb;
  ushort16* hb = hn;
  ushort16* t2 = ob;

  prep_w<<<dim3(3168), 256, 0, stream>>>(wq, wk, wv, wo, ff_w1, ff_w2, lt_w, pre_w1,
                                         qkv_t, wo_t, w1_t, w2_t, lt_t, pw1_t);
  conv_bf16<<<dim3((BS_ * 64 + 255) / 256), 256, 0, stream>>>(x, conv_w, conv_b, p);

  const int MB = (BS_ + 127) / 128;  // 466
  gemm_bf16<E_H0><<<dim3(1, MB), 256, 0, stream>>>(p, 64, lt_t, 64, h, nullptr, 128, lt_b, pos, BS_, 64);

  int lnBlocks = (BS_ + 3) / 4;
  for (int l = 0; l < 4; l++) {
    ln_bf16<<<dim3(lnBlocks), 256, 0, stream>>>(h, hn, ln1_s + l * 128, ln1_b + l * 128, BS_);
    gemm_bf16<E_BF16><<<dim3(3, MB), 256, 0, stream>>>(hn, 128, qkv_t + (size_t)l * 49152, 128,
                                                       nullptr, qkvb, 384, nullptr, nullptr, BS_, 128);
    attn3<<<dim3(B_ * H_ * NW_), 64, 0, stream>>>(qkvb, ob);
    gemm_bf16<E_RES><<<dim3(1, MB), 256, 0, stream>>>(ob, 128, wo_t + (size_t)l * 16384, 128,
                                                      h, nullptr, 128, wo_b + l * 128, nullptr, BS_, 128);
    ln_bf16<<<dim3(lnBlocks), 256, 0, stream>>>(h, hn, ln2_s + l * 128, ln2_b + l * 128, BS_);
    gemm_bf16<E_GELU><<<dim3(4, MB), 256, 0, stream>>>(hn, 128, w1_t + (size_t)l * 65536, 128,
                                                       nullptr, t, 512, ff_b1 + l * 512, nullptr, BS_, 128);
    if (l < 3) {
      gemm_bf16<E_RES><<<dim3(1, MB), 256, 0, stream>>>(t, 512, w2_t + (size_t)l * 65536, 512,
                                                        h, nullptr, 128, ff_b2 + l * 128, nullptr, BS_, 512);
    } else {
      gemm_bf16<E_RESBF><<<dim3(1, MB), 256, 0, stream>>>(t, 512, w2_t + (size_t)l * 65536, 512,
                                                          h, hb, 128, ff_b2 + l * 128, nullptr, BS_, 512);
    }
  }
  gemm_bf16<E_RELU><<<dim3(1, MB), 256, 0, stream>>>(hb, 128, pw1_t, 128,
                                                     nullptr, t2, 128, pre_b1, nullptr, BS_, 128);
  head2<<<dim3(lnBlocks), 256, 0, stream>>>(t2, pre_w2, pre_b2, (float*)d_out, BS_);
}

// Round 7
// 1145.637 us; speedup vs baseline: 3.6461x; 1.0171x over previous
//
#include <hip/hip_runtime.h>
#include <math.h>

#define B_   16
#define S1_  61
#define S_   3721
#define D_   128
#define H_   8
#define NW_  61
#define FF_  512
#define BS_  (B_*S_)   // 59536

typedef unsigned int   uint32;
typedef unsigned short ushort16;
typedef __attribute__((ext_vector_type(8))) short  short8;
typedef __attribute__((ext_vector_type(4))) float  floatx4;

__device__ __forceinline__ ushort16 f2bf(float f) {
  uint32 u = __float_as_uint(f);
  uint32 r = u + 0x7fffu + ((u >> 16) & 1u);   // RNE
  return (ushort16)(r >> 16);
}
__device__ __forceinline__ short bfs(float f) {  // bf16 RNE as short
  uint32 u = __float_as_uint(f);
  return (short)((u + 0x7fffu + ((u >> 16) & 1u)) >> 16);
}
__device__ __forceinline__ float bf2f(short s) { // bf16 bits -> float
  return __uint_as_float(((uint32)(ushort16)s) << 16);
}

// ---------------- weight prep: fp32 -> bf16, transposed to [N][K] ----------------
__global__ __launch_bounds__(256) void prep_w(
    const float* __restrict__ wq, const float* __restrict__ wk, const float* __restrict__ wv,
    const float* __restrict__ wo, const float* __restrict__ w1, const float* __restrict__ w2,
    const float* __restrict__ lt, const float* __restrict__ pw1,
    const float* __restrict__ cw, const float* __restrict__ cb,
    ushort16* __restrict__ qkv_t, ushort16* __restrict__ wo_t, ushort16* __restrict__ w1_t,
    ushort16* __restrict__ w2_t, ushort16* __restrict__ lt_t, ushort16* __restrict__ pw1_t,
    ushort16* __restrict__ wc_t, float* __restrict__ cb_pad) {
  int i = blockIdx.x * 256 + threadIdx.x;
  if (i < 196608) {                       // qkv: [l][n(384)][k(128)]
    int l = i / 49152, r = i % 49152;
    int n = r / 128, k = r % 128;
    const float* src = (n < 128) ? wq : (n < 256) ? wk : wv;
    qkv_t[i] = f2bf(src[(l * 128 + k) * 128 + (n & 127)]);
  } else if (i < 262144) {                // wo: [l][n][k]
    int j = i - 196608;
    int l = j / 16384, r = j % 16384;
    int n = r / 128, k = r % 128;
    wo_t[j] = f2bf(wo[(l * 128 + k) * 128 + n]);
  } else if (i < 524288) {                // w1: [l][n(512)][k(128)]
    int j = i - 262144;
    int l = j / 65536, r = j % 65536;
    int n = r / 128, k = r % 128;
    w1_t[j] = f2bf(w1[(size_t)l * 65536 + k * 512 + n]);
  } else if (i < 786432) {                // w2: [l][n(128)][k(512)]
    int j = i - 524288;
    int l = j / 65536, r = j % 65536;
    int n = r / 512, k = r % 512;
    w2_t[j] = f2bf(w2[(size_t)l * 65536 + k * 128 + n]);
  } else if (i < 794624) {                // lt: [n(128)][k(64 padded from 49)]
    int j = i - 786432;
    int n = j / 64, k = j % 64;
    lt_t[j] = f2bf(k < 49 ? lt[k * 128 + n] : 0.f);
  } else if (i < 811008) {                // pre_w1: [n][k]
    int j = i - 794624;
    int n = j / 128, k = j % 128;
    pw1_t[j] = f2bf(pw1[k * 128 + n]);
  } else if (i < 815104) {                // conv w: [c(64)][tap(64)], zero-padded
    int j = i - 811008;
    int n = j >> 6, k = j & 63;
    wc_t[j] = f2bf((n < 49 && k < 49) ? cw[n * 49 + k] : 0.f);
  } else if (i < 815168) {                // padded conv bias (64 floats)
    int j = i - 815104;
    cb_pad[j] = (j < 49) ? cb[j] : 0.f;
  }
}

// ---------------- im2col: x [B,61,61] fp32 -> X [BS][64] bf16 (taps, zero pad) ----
__global__ __launch_bounds__(256) void im2col_k(const float* __restrict__ x,
                                                ushort16* __restrict__ X) {
  int t = blockIdx.x * 256 + threadIdx.x;
  if (t >= BS_ * 64) return;
  int tap = t & 63;
  int row = t >> 6;
  if (tap >= 49) { X[t] = 0; return; }
  int b = row / S_, s = row % S_;
  int i = s / S1_, j = s % S1_;
  int di = tap / 7, dj = tap % 7;
  int ii = i + di - 3, jj = j + dj - 3;
  float v = 0.f;
  if ((unsigned)ii < (unsigned)S1_ && (unsigned)jj < (unsigned)S1_)
    v = x[(b * S1_ + ii) * S1_ + jj];
  X[t] = f2bf(v);
}

// ---------------- bf16 MFMA GEMM: C[M x N] = A[M x K] * Bt[N x K]^T ----------------
// E_H0LN / E_RESLN additionally fuse LayerNorm over the full 128-wide row
// (requires grid.x == 1, N == 128): H gets the pre-LN value, Cb gets LN'd bf16.
enum { E_BF16 = 0, E_H0LN = 1, E_RESLN = 2, E_GELU = 3, E_RELU = 4, E_RESBF = 5 };

template <int EPI>
__global__ __launch_bounds__(256) void gemm_bf16(
    const ushort16* __restrict__ A, int lda,
    const ushort16* __restrict__ Bt, int ldbt,
    float* __restrict__ H,
    ushort16* __restrict__ Cb, int ldc,
    const float* __restrict__ bias,
    const float* __restrict__ pos,
    const float* __restrict__ ls,   // LN scale (E_*LN)
    const float* __restrict__ lb,   // LN bias  (E_*LN)
    int M, int N, int K) {
  __shared__ ushort16 As[128][72];
  __shared__ ushort16 Bs[128][72];
  __shared__ float stats[128][2][2];   // [row][col-wave][sum, sumsq]
  int bm = blockIdx.y * 128, bn = blockIdx.x * 128;
  int tid = threadIdx.x;
  int lane = tid & 63, wave = tid >> 6;
  int wm = (wave >> 1) * 64, wn = (wave & 1) * 64;
  int ln = lane & 15, qd = lane >> 4;
  floatx4 acc[4][4] = {};
  for (int kc = 0; kc < K; kc += 64) {
    #pragma unroll
    for (int u = 0; u < 4; u++) {
      int id = tid + u * 256;
      int row = id >> 3, c = (id & 7) * 8;
      int gm = bm + row; if (gm > M - 1) gm = M - 1;
      int gn = bn + row; if (gn > N - 1) gn = N - 1;
      *(uint4*)&As[row][c] = *(const uint4*)(A + (size_t)gm * lda + kc + c);
      *(uint4*)&Bs[row][c] = *(const uint4*)(Bt + (size_t)gn * ldbt + kc + c);
    }
    __syncthreads();
    #pragma unroll
    for (int ks = 0; ks < 64; ks += 32) {
      short8 af[4], bf[4];
      #pragma unroll
      for (int i = 0; i < 4; i++) af[i] = *(const short8*)&As[wm + i * 16 + ln][ks + qd * 8];
      #pragma unroll
      for (int j = 0; j < 4; j++) bf[j] = *(const short8*)&Bs[wn + j * 16 + ln][ks + qd * 8];
      #pragma unroll
      for (int i = 0; i < 4; i++)
        #pragma unroll
        for (int j = 0; j < 4; j++)
          acc[i][j] = __builtin_amdgcn_mfma_f32_16x16x32_bf16(af[i], bf[j], acc[i][j], 0, 0, 0);
    }
    __syncthreads();
  }

  if (EPI == E_H0LN || EPI == E_RESLN) {
    // ---- fused residual/bias + LayerNorm epilogue (full row per block) ----
    float lsv[4], lbv[4];
    #pragma unroll
    for (int j = 0; j < 4; j++) {
      int gn = wn + j * 16 + ln;     // bn == 0
      lsv[j] = ls[gn]; lbv[j] = lb[gn];
    }
    int wI = wn >> 6;
    #pragma unroll
    for (int i = 0; i < 4; i++) {
      #pragma unroll
      for (int r = 0; r < 4; r++) {
        int lrow = wm + i * 16 + qd * 4 + r;
        int gm = bm + lrow;
        float s1 = 0.f, s2 = 0.f;
        #pragma unroll
        for (int j = 0; j < 4; j++) {
          int gn = wn + j * 16 + ln;
          float v = acc[i][j][r];
          float g;
          if (EPI == E_H0LN) g = v + bias[gn] + pos[(size_t)(gm % S_) * 128 + gn];
          else               g = H[(size_t)gm * 128 + gn] + v + bias[gn];
          acc[i][j][r] = g;
          if (gm < M) H[(size_t)gm * 128 + gn] = g;
          s1 += g; s2 += g * g;
        }
        #pragma unroll
        for (int off = 1; off <= 8; off <<= 1) {
          s1 += __shfl_xor(s1, off);
          s2 += __shfl_xor(s2, off);
        }
        if (ln == 0) { stats[lrow][wI][0] = s1; stats[lrow][wI][1] = s2; }
      }
    }
    __syncthreads();
    #pragma unroll
    for (int i = 0; i < 4; i++) {
      #pragma unroll
      for (int r = 0; r < 4; r++) {
        int lrow = wm + i * 16 + qd * 4 + r;
        int gm = bm + lrow;
        if (gm >= M) continue;
        float s1 = stats[lrow][0][0] + stats[lrow][1][0];
        float s2 = stats[lrow][0][1] + stats[lrow][1][1];
        float mean = s1 * (1.f / 128.f);
        float var  = s2 * (1.f / 128.f) - mean * mean;
        float inv  = rsqrtf(fmaxf(var, 0.f) + 1e-5f);
        #pragma unroll
        for (int j = 0; j < 4; j++) {
          int gn = wn + j * 16 + ln;
          Cb[(size_t)gm * 128 + gn] = f2bf((acc[i][j][r] - mean) * inv * lsv[j] + lbv[j]);
        }
      }
    }
  } else {
    #pragma unroll
    for (int i = 0; i < 4; i++) {
      #pragma unroll
      for (int r = 0; r < 4; r++) {
        int gm = bm + wm + i * 16 + qd * 4 + r;
        if (gm >= M) continue;
        #pragma unroll
        for (int j = 0; j < 4; j++) {
          int gn = bn + wn + j * 16 + ln;
          if (gn >= N) continue;
          float v = acc[i][j][r];
          if (EPI == E_BF16) {
            Cb[(size_t)gm * ldc + gn] = f2bf(v);
          } else if (EPI == E_GELU) {
            float g = v + bias[gn];
            g = 0.5f * g * (1.f + erff(g * 0.70710678118654752f));
            Cb[(size_t)gm * ldc + gn] = f2bf(g);
          } else if (EPI == E_RELU) {
            float g = fmaxf(v + bias[gn], 0.f);
            Cb[(size_t)gm * ldc + gn] = f2bf(g);
          } else if (EPI == E_RESBF) {
            size_t o = (size_t)gm * 128 + gn;
            float g = H[o] + v + bias[gn];
            H[o] = g;
            Cb[(size_t)gm * ldc + gn] = f2bf(g);
          }
        }
      }
    }
  }
}

// ---------------- MFMA windowed attention, two-part P split: one wave per (b,h,w) --
__global__ __launch_bounds__(64) void attn3(const ushort16* __restrict__ qkv,
                                            ushort16* __restrict__ o) {
  int bid = blockIdx.x;
  int w  = bid % NW_;
  int hh = (bid / NW_) % H_;
  int b  = bid / (NW_ * H_);
  __shared__ ushort16 Kl[192][16];
  __shared__ ushort16 Vl[192][16];
  int lane = threadIdx.x;
  int qcol = lane & 15, quad = lane >> 4;

  for (int i = lane; i < 768; i += 64) {
    int isV = (i >= 384) ? 1 : 0;
    int r2 = isV ? (i - 384) : i;
    int j = r2 >> 1, half = (r2 & 1) * 8;
    int krow = (w - 1) * 61 + j;
    uint4 val = make_uint4(0u, 0u, 0u, 0u);
    if (j < 183 && (unsigned)krow < (unsigned)S_) {
      val = *(const uint4*)(qkv + ((size_t)(b * S_ + krow) * 384 + (isV ? 256 : 128) + hh * 16 + half));
    }
    if (isV) *(uint4*)&Vl[j][half] = val;
    else     *(uint4*)&Kl[j][half] = val;
  }

  short8 qf[4];
  #pragma unroll
  for (int qt = 0; qt < 4; qt++) {
    int qloc = qt * 16 + qcol;
    if (qloc > 60) qloc = 60;
    const uint32* qp = (const uint32*)(qkv + ((size_t)(b * S_ + w * 61 + qloc) * 384 + hh * 16 + quad * 4));
    uint32 u0 = qp[0], u1 = qp[1];
    short8 f = (short8)0;
    f[0] = (short)(u0 & 0xffffu); f[1] = (short)(u0 >> 16);
    f[2] = (short)(u1 & 0xffffu); f[3] = (short)(u1 >> 16);
    qf[qt] = f;
  }
  __syncthreads();

  int j0 = (w == 0) ? 61 : 0;
  int j1 = (w == NW_ - 1) ? 122 : 183;
  int kt0 = (w == 0) ? 3 : 0;
  int kt1 = (w == NW_ - 1) ? 8 : 12;

  floatx4 oacc[4];
  #pragma unroll
  for (int qt = 0; qt < 4; qt++) { oacc[qt][0]=0.f; oacc[qt][1]=0.f; oacc[qt][2]=0.f; oacc[qt][3]=0.f; }
  float lsum[4] = {0.f, 0.f, 0.f, 0.f};
  const floatx4 zero4 = {0.f, 0.f, 0.f, 0.f};

  for (int kt = kt0; kt < kt1; kt++) {
    const uint32* kp = (const uint32*)&Kl[kt * 16 + qcol][quad * 4];
    uint32 k0 = kp[0], k1 = kp[1];
    short8 kf = (short8)0;
    kf[0] = (short)(k0 & 0xffffu); kf[1] = (short)(k0 >> 16);
    kf[2] = (short)(k1 & 0xffffu); kf[3] = (short)(k1 >> 16);

    int kb = kt * 16 + quad * 4;
    short8 vf = (short8)0;
    vf[0] = (short)Vl[kb + 0][qcol];
    vf[1] = (short)Vl[kb + 1][qcol];
    vf[2] = (short)Vl[kb + 2][qcol];
    vf[3] = (short)Vl[kb + 3][qcol];

    floatx4 sacc[4];
    #pragma unroll
    for (int qt = 0; qt < 4; qt++)
      sacc[qt] = __builtin_amdgcn_mfma_f32_16x16x32_bf16(kf, qf[qt], zero4, 0, 0, 0);

    bool v0 = (unsigned)(kb + 0 - j0) < (unsigned)(j1 - j0);
    bool v1 = (unsigned)(kb + 1 - j0) < (unsigned)(j1 - j0);
    bool v2 = (unsigned)(kb + 2 - j0) < (unsigned)(j1 - j0);
    bool v3 = (unsigned)(kb + 3 - j0) < (unsigned)(j1 - j0);
    #pragma unroll
    for (int qt = 0; qt < 4; qt++) {
      float e0 = v0 ? __expf(fminf(sacc[qt][0] * 0.25f, 60.f)) : 0.f;
      float e1 = v1 ? __expf(fminf(sacc[qt][1] * 0.25f, 60.f)) : 0.f;
      float e2 = v2 ? __expf(fminf(sacc[qt][2] * 0.25f, 60.f)) : 0.f;
      float e3 = v3 ? __expf(fminf(sacc[qt][3] * 0.25f, 60.f)) : 0.f;
      lsum[qt] += (e0 + e1) + (e2 + e3);
      short h0 = bfs(e0), h1 = bfs(e1), h2 = bfs(e2), h3 = bfs(e3);
      short8 ph = (short8)0, pl = (short8)0;
      ph[0] = h0; ph[1] = h1; ph[2] = h2; ph[3] = h3;
      pl[0] = bfs(e0 - bf2f(h0));
      pl[1] = bfs(e1 - bf2f(h1));
      pl[2] = bfs(e2 - bf2f(h2));
      pl[3] = bfs(e3 - bf2f(h3));
      oacc[qt] = __builtin_amdgcn_mfma_f32_16x16x32_bf16(ph, vf, oacc[qt], 0, 0, 0);
      oacc[qt] = __builtin_amdgcn_mfma_f32_16x16x32_bf16(pl, vf, oacc[qt], 0, 0, 0);
    }
  }

  #pragma unroll
  for (int qt = 0; qt < 4; qt++) {
    float l = lsum[qt];
    l += __shfl_xor(l, 16);
    l += __shfl_xor(l, 32);
    lsum[qt] = 1.0f / fmaxf(l, 1e-30f);
  }
  #pragma unroll
  for (int qt = 0; qt < 4; qt++) {
    #pragma unroll
    for (int r = 0; r < 4; r++) {
      int qloc = qt * 16 + quad * 4 + r;
      float invl = __shfl(lsum[qt], quad * 4 + r);
      if (qloc < 61) {
        size_t row = (size_t)b * S_ + w * 61 + qloc;
        o[row * 128 + hh * 16 + qcol] = f2bf(oacc[qt][r] * invl);
      }
    }
  }
}

// ---------------- head finish ----------------
__global__ __launch_bounds__(256) void head2(const ushort16* __restrict__ t2,
                                             const float* __restrict__ w2,
                                             const float* __restrict__ b2,
                                             float* __restrict__ out, int rows) {
  int wv = (blockIdx.x * 256 + threadIdx.x) >> 6;
  int lane = threadIdx.x & 63;
  if (wv >= rows) return;
  uint32 u = *(const uint32*)(t2 + (size_t)wv * 128 + lane * 2);
  float a = __uint_as_float(u << 16) * w2[lane * 2]
          + __uint_as_float(u & 0xffff0000u) * w2[lane * 2 + 1];
  #pragma unroll
  for (int off = 32; off; off >>= 1) a += __shfl_xor(a, off);
  if (lane == 0) out[wv] = a + b2[0];
}

extern "C" void kernel_launch(void* const* d_in, const int* in_sizes, int n_in,
                              void* d_out, int out_size, void* d_ws, size_t ws_size,
                              hipStream_t stream) {
  const float* x      = (const float*)d_in[0];
  const float* conv_w = (const float*)d_in[1];
  const float* conv_b = (const float*)d_in[2];
  const float* lt_w   = (const float*)d_in[3];
  const float* lt_b   = (const float*)d_in[4];
  const float* pos    = (const float*)d_in[5];
  const float* ln1_s  = (const float*)d_in[6];
  const float* ln1_b  = (const float*)d_in[7];
  const float* wq     = (const float*)d_in[8];
  const float* wk     = (const float*)d_in[9];
  const float* wv     = (const float*)d_in[10];
  const float* wo     = (const float*)d_in[11];
  const float* wo_b   = (const float*)d_in[12];
  const float* ln2_s  = (const float*)d_in[13];
  const float* ln2_b  = (const float*)d_in[14];
  const float* ff_w1  = (const float*)d_in[15];
  const float* ff_b1  = (const float*)d_in[16];
  const float* ff_w2  = (const float*)d_in[17];
  const float* ff_b2  = (const float*)d_in[18];
  const float* pre_w1 = (const float*)d_in[19];
  const float* pre_b1 = (const float*)d_in[20];
  const float* pre_w2 = (const float*)d_in[21];
  const float* pre_b2 = (const float*)d_in[22];

  char* ws = (char*)d_ws;
  const size_t SZ_H   = (size_t)BS_ * 128 * 4;
  const size_t SZ_HN  = (size_t)BS_ * 128 * 2;
  const size_t SZ_QKV = (size_t)BS_ * 384 * 2;
  const size_t SZ_O   = (size_t)BS_ * 128 * 2;
  float*    h    = (float*)ws;
  ushort16* hn   = (ushort16*)(ws + SZ_H);
  ushort16* qkvb = (ushort16*)(ws + SZ_H + SZ_HN);              // also p, t
  ushort16* ob   = (ushort16*)(ws + SZ_H + SZ_HN + SZ_QKV);     // also X, t2
  char*     wsw  = ws + SZ_H + SZ_HN + SZ_QKV + SZ_O;
  ushort16* qkv_t = (ushort16*)(wsw);
  ushort16* wo_t  = qkv_t + 196608;
  ushort16* w1_t  = wo_t  + 65536;
  ushort16* w2_t  = w1_t  + 262144;
  ushort16* lt_t  = w2_t  + 262144;
  ushort16* pw1_t = lt_t  + 8192;
  ushort16* wc_t  = pw1_t + 16384;
  float*    cb_pad = (float*)(wc_t + 4096);
  ushort16* X  = ob;        // im2col patches [BS][64] bf16
  ushort16* p  = qkvb;      // conv output (post-relu) [BS][64] bf16
  ushort16* t  = qkvb;      // FF intermediate [BS][512]
  ushort16* hb = hn;        // bf16 copy of final h
  ushort16* t2 = ob;        // head hidden [BS][128]

  prep_w<<<dim3(3185), 256, 0, stream>>>(wq, wk, wv, wo, ff_w1, ff_w2, lt_w, pre_w1,
                                         conv_w, conv_b,
                                         qkv_t, wo_t, w1_t, w2_t, lt_t, pw1_t, wc_t, cb_pad);
  im2col_k<<<dim3((BS_ * 64 + 255) / 256), 256, 0, stream>>>(x, X);

  const int MB = (BS_ + 127) / 128;  // 466
  // p = relu(X @ Wc^T + cb)
  gemm_bf16<E_RELU><<<dim3(1, MB), 256, 0, stream>>>(X, 64, wc_t, 64, nullptr, p, 64,
                                                     cb_pad, nullptr, nullptr, nullptr, BS_, 64, 64);
  // h = p @ lt_w + lt_b + pos ; hn = LN1_0(h)
  gemm_bf16<E_H0LN><<<dim3(1, MB), 256, 0, stream>>>(p, 64, lt_t, 64, h, hn, 128,
                                                     lt_b, pos, ln1_s, ln1_b, BS_, 128, 64);

  for (int l = 0; l < 4; l++) {
    gemm_bf16<E_BF16><<<dim3(3, MB), 256, 0, stream>>>(hn, 128, qkv_t + (size_t)l * 49152, 128,
                                                       nullptr, qkvb, 384, nullptr, nullptr,
                                                       nullptr, nullptr, BS_, 384, 128);
    attn3<<<dim3(B_ * H_ * NW_), 64, 0, stream>>>(qkvb, ob);
    // h += o @ wo + wo_b ; hn = LN2_l(h)
    gemm_bf16<E_RESLN><<<dim3(1, MB), 256, 0, stream>>>(ob, 128, wo_t + (size_t)l * 16384, 128,
                                                        h, hn, 128, wo_b + l * 128, nullptr,
                                                        ln2_s + l * 128, ln2_b + l * 128, BS_, 128, 128);
    gemm_bf16<E_GELU><<<dim3(4, MB), 256, 0, stream>>>(hn, 128, w1_t + (size_t)l * 65536, 128,
                                                       nullptr, t, 512, ff_b1 + l * 512, nullptr,
                                                       nullptr, nullptr, BS_, 512, 128);
    if (l < 3) {
      // h += t @ w2 + b2 ; hn = LN1_{l+1}(h)
      gemm_bf16<E_RESLN><<<dim3(1, MB), 256, 0, stream>>>(t, 512, w2_t + (size_t)l * 65536, 512,
                                                          h, hn, 128, ff_b2 + l * 128, nullptr,
                                                          ln1_s + (l + 1) * 128, ln1_b + (l + 1) * 128,
                                                          BS_, 128, 512);
    } else {  // final: h += ... and hb = bf16(h) for the head
      gemm_bf16<E_RESBF><<<dim3(1, MB), 256, 0, stream>>>(t, 512, w2_t + (size_t)l * 65536, 512,
                                                          h, hb, 128, ff_b2 + l * 128, nullptr,
                                                          nullptr, nullptr, BS_, 128, 512);
    }
  }
  gemm_bf16<E_RELU><<<dim3(1, MB), 256, 0, stream>>>(hb, 128, pw1_t, 128,
                                                     nullptr, t2, 128, pre_b1, nullptr,
                                                     nullptr, nullptr, BS_, 128, 128);
  head2<<<dim3((BS_ + 3) / 4), 256, 0, stream>>>(t2, pre_w2, pre_b2, (float*)d_out, BS_);
}